// Round 15
// baseline (182.175 us; speedup 1.0000x reference)
//
#include <hip/hip_runtime.h>

#define NB 8
#define CIN 3
#define N0 327680
#define N1 81920
#define N2 20480
#define KC 10
#define KA 4

typedef __attribute__((ext_vector_type(8))) short bf16x8;
typedef __attribute__((ext_vector_type(4))) float f32x4;
typedef int4  __attribute__((aligned(4))) int4_u;

__device__ __forceinline__ unsigned f2bf(float f) {          // RNE float->bf16
  unsigned u = __float_as_uint(f);
  return (u + 0x7FFFu + ((u >> 16) & 1u)) >> 16;
}

union bfrag { bf16x8 v; unsigned u[4]; };

// ---- fused prep: blocks [0,1280) transx | [1280,2560) fidx | [2560,3360) hist |
// [3360,3380) weight-prep.  A12/G zeroed by hipMemsetAsync beforehand. ----
__global__ __launch_bounds__(256) void kpre(
    const float* __restrict__ x, uint4* __restrict__ xT64,
    const int* __restrict__ conv_t0, const int* __restrict__ conv_t1,
    const int* __restrict__ conv_t2,
    const int* __restrict__ adj0, const int* __restrict__ adj1,
    const int* __restrict__ pool0, const int* __restrict__ pool1,
    int* __restrict__ fidxM, int* __restrict__ fidxP, float* __restrict__ A12,
    const float* __restrict__ w1, const float* __restrict__ w2,
    const float* __restrict__ w3, const float* __restrict__ b3,
    unsigned short* __restrict__ wB1, unsigned short* __restrict__ wB,
    float* __restrict__ w3t, float* __restrict__ out) {
  int blk = blockIdx.x;
  if (blk < 1280) {
    // ---- x -> xT64 [n][64B]: 4 bpair-triples {c0|c1, c2|c0', c1'|c2'} + 16B pad ----
    int n = blk * 256 + threadIdx.x;
    unsigned d[12];
#pragma unroll
    for (int bp = 0; bp < 4; ++bp) {
      const float* pe = x + (size_t)(2 * bp) * CIN * N0 + n;       // even batch
      const float* po = pe + (size_t)CIN * N0;                    // odd batch
      float e0 = pe[0], e1 = pe[N0], e2 = pe[2 * N0];
      float o0 = po[0], o1 = po[N0], o2 = po[2 * N0];
      d[bp * 3 + 0] = f2bf(e0) | (f2bf(e1) << 16);
      d[bp * 3 + 1] = f2bf(e2) | (f2bf(o0) << 16);
      d[bp * 3 + 2] = f2bf(o1) | (f2bf(o2) << 16);
    }
    uint4* dst = xT64 + (size_t)n * 4;
    dst[0] = make_uint4(d[0], d[1], d[2], d[3]);
    dst[1] = make_uint4(d[4], d[5], d[6], d[7]);
    dst[2] = make_uint4(d[8], d[9], d[10], d[11]);
    dst[3] = make_uint4(0, 0, 0, 0);
  } else if (blk < 2560) {
    // ---- index tables ----
    // fidxM row (48B): [t0 t1 t8 t9 | t2 t3 t4 t5 | t6 t7 0 0]  (byte offs, x64)
    // fidxP row (48B): [e0 e2 e4 e6 | e8 0 o1 o3 | o5 o7 o9 0]  (byte offs, x32)
    int t = (blk - 1280) * 256 + threadIdx.x;   // N1*4 threads
    int j = t >> 2, p = t & 3;
    int pj = pool0[j];
    int pos = adj0[pj * KA + p];
    const int2* s0 = (const int2*)(conv_t0 + (size_t)pos * 10);
    int2 q0 = s0[0], q1 = s0[1], q2 = s0[2], q3 = s0[3], q4 = s0[4];
    int4_u* dM = (int4_u*)(fidxM + (size_t)t * 12);
    dM[0] = make_int4(q0.x * 64, q0.y * 64, q4.x * 64, q4.y * 64);
    dM[1] = make_int4(q1.x * 64, q1.y * 64, q2.x * 64, q2.y * 64);
    dM[2] = make_int4(q3.x * 64, q3.y * 64, 0, 0);
    if (j < N2) {
      int qj = pool1[j];
      int qos = adj1[qj * KA + p];
      const int2* s1 = (const int2*)(conv_t1 + (size_t)qos * 10);
      int2 r0 = s1[0], r1 = s1[1], r2 = s1[2], r3 = s1[3], r4 = s1[4];
      int4_u* dP = (int4_u*)(fidxP + (size_t)t * 12);
      dP[0] = make_int4(r0.x * 32, r1.x * 32, r2.x * 32, r3.x * 32);
      dP[1] = make_int4(r4.x * 32, 0,          r0.y * 32, r1.y * 32);
      dP[2] = make_int4(r2.y * 32, r3.y * 32, r4.y * 32, 0);
    }
  } else if (blk < 3360) {
    // ---- histogram A[n][k] = #{j: conv_t2[j,k] = n} ----
    int t = (blk - 2560) * 256 + threadIdx.x;   // N2*10 threads
    int n = conv_t2[t];
    int k = t % 10;
    atomicAdd(&A12[n * 12 + k], 1.0f);
  } else {
    // ---- weight prep ----
    int t = (blk - 3360) * 256 + threadIdx.x;
    if (t < 1024) {
      int ch = t >> 9, rest = t & 511, l = rest >> 3, e = rest & 7;
      int k = ch * 32 + ((l >> 4) * 8) + e;
      int tap = k >> 2, cc = k & 3;
      float v = (tap < KC && cc < CIN) ? w1[((l & 15) * CIN + cc) * KC + tap] : 0.f;
      wB1[t] = (unsigned short)f2bf(v);
    }
    if (t < 5120) {
      int e = t & 7, l = (t >> 3) & 63, nt = (t >> 9) & 1, q = t >> 10;
      int kc = q * 32 + ((l >> 4) * 8) + e;
      int tap = kc >> 4, c = kc & 15;
      int o = nt * 16 + (l & 15);
      wB[t] = (unsigned short)f2bf(w2[(o * 16 + c) * KC + tap]);
    }
    if (t < 3200) { int o = t % 10, r = t / 10, c = r & 31, k = r >> 5;
                    w3t[t] = w3[(o * 32 + c) * KC + k]; }
    if (t < 80)   out[t] = b3[t % 10];
  }
}

// dword triple of bpair s (s compile-time) from a 12-dword row (Ra,Rb,Rc)
#define TR0(s) ((s) == 0 ? Ra.x : (s) == 1 ? Ra.w : (s) == 2 ? Rb.z : Rc.y)
#define TR1(s) ((s) == 0 ? Ra.y : (s) == 1 ? Rb.x : (s) == 2 ? Rb.w : Rc.z)
#define TR2(s) ((s) == 0 ? Ra.z : (s) == 1 ? Rb.y : (s) == 2 ? Rc.x : Rc.w)

// ---- conv1 (3->16) + maxpool0 via MFMA gather-GEMM. 1 tile/wave, 8 waves/SIMD
// for max outstanding misses; hi>=1 lanes skip taps-8/9 loads (B1 rows zero). ----
__global__ __launch_bounds__(256, 8) void k1(
    const char* __restrict__ xT64, const int* __restrict__ fidxM,
    const bf16x8* __restrict__ wB1, const float* __restrict__ b1,
    unsigned short* __restrict__ h2) {
  int blk = blockIdx.x;                         // 5120 blocks x 4 waves = 20480 tiles
  int wave = threadIdx.x >> 6;
  int lane = threadIdx.x & 63;
  int col = lane & 15, hi = lane >> 4;
  int tile = blk * 4 + wave;
  bf16x8 B0 = wB1[lane];
  bf16x8 B1 = wB1[64 + lane];
  float bias = b1[col];
  int seloff = ((hi + 1) >> 1) << 2;            // ints: hi->{0,4,4,8}

  int4 I = *(const int4_u*)(fidxM + ((size_t)tile * 16 + col) * 12 + seloff);
  int a0 = (hi == 2) ? I.z : I.x;               // tap 2hi
  int a1 = (hi == 2) ? I.w : I.y;               // tap 2hi+1
  const uint4* r0p = (const uint4*)(xT64 + a0);
  const uint4* r1p = (const uint4*)(xT64 + a1);
  uint4 R0a = r0p[0], R0b = r0p[1], R0c = r0p[2];
  uint4 R1a = r1p[0], R1b = r1p[1], R1c = r1p[2];
  uint4 zz = make_uint4(0, 0, 0, 0);
  uint4 R2a = zz, R2b = zz, R2c = zz, R3a = zz, R3b = zz, R3c = zz;
  if (hi == 0) {                                // taps 8,9 real only for hi=0
    const uint4* r2p = (const uint4*)(xT64 + I.z);
    const uint4* r3p = (const uint4*)(xT64 + I.w);
    R2a = r2p[0]; R2b = r2p[1]; R2c = r2p[2];
    R3a = r3p[0]; R3b = r3p[1]; R3c = r3p[2];
  }
  size_t j = (size_t)tile * 4 + hi;
  unsigned short* dst = h2 + j * 16 + col;

#define DO_BPAIR(s)                                                           \
  {                                                                           \
    unsigned t0, t1, t2, u0, u1, u2, v0, v1, v2, w0, w1, w2;                  \
    { uint4 Ra = R0a, Rb = R0b, Rc = R0c;                                     \
      t0 = TR0(s); t1 = TR1(s); t2 = TR2(s); }                                \
    { uint4 Ra = R1a, Rb = R1b, Rc = R1c;                                     \
      u0 = TR0(s); u1 = TR1(s); u2 = TR2(s); }                                \
    { uint4 Ra = R2a, Rb = R2b, Rc = R2c;                                     \
      v0 = TR0(s); v1 = TR1(s); v2 = TR2(s); }                                \
    { uint4 Ra = R3a, Rb = R3b, Rc = R3c;                                     \
      w0 = TR0(s); w1 = TR1(s); w2 = TR2(s); }                                \
    bfrag A0c0, A1c0, A0c1, A1c1;                                             \
    A0c0.u[0] = t0; A0c0.u[1] = t1 & 0xFFFFu;                                 \
    A0c0.u[2] = u0; A0c0.u[3] = u1 & 0xFFFFu;                                 \
    A1c0.u[0] = (t1 >> 16) | (t2 << 16); A1c0.u[1] = t2 >> 16;                \
    A1c0.u[2] = (u1 >> 16) | (u2 << 16); A1c0.u[3] = u2 >> 16;                \
    A0c1.u[0] = v0; A0c1.u[1] = v1 & 0xFFFFu;                                 \
    A0c1.u[2] = w0; A0c1.u[3] = w1 & 0xFFFFu;                                 \
    A1c1.u[0] = (v1 >> 16) | (v2 << 16); A1c1.u[1] = v2 >> 16;                \
    A1c1.u[2] = (w1 >> 16) | (w2 << 16); A1c1.u[3] = w2 >> 16;                \
    f32x4 z = {0.f, 0.f, 0.f, 0.f};                                           \
    f32x4 acc0 = __builtin_amdgcn_mfma_f32_16x16x32_bf16(A0c0.v, B0, z, 0, 0, 0); \
    acc0 = __builtin_amdgcn_mfma_f32_16x16x32_bf16(A0c1.v, B1, acc0, 0, 0, 0);    \
    f32x4 acc1 = __builtin_amdgcn_mfma_f32_16x16x32_bf16(A1c0.v, B0, z, 0, 0, 0); \
    acc1 = __builtin_amdgcn_mfma_f32_16x16x32_bf16(A1c1.v, B1, acc1, 0, 0, 0);    \
    float m0 = fmaxf(fmaxf(acc0[0], acc0[1]), fmaxf(acc0[2], acc0[3])) + bias;    \
    float m1 = fmaxf(fmaxf(acc1[0], acc1[1]), fmaxf(acc1[2], acc1[3])) + bias;    \
    dst[(size_t)(2 * (s)) * N1 * 16]     = (unsigned short)f2bf(m0);          \
    dst[(size_t)(2 * (s) + 1) * N1 * 16] = (unsigned short)f2bf(m1);          \
  }
  DO_BPAIR(0)
  DO_BPAIR(1)
  DO_BPAIR(2)
  DO_BPAIR(3)
#undef DO_BPAIR
}

// ---- conv2 (16->32) + maxpool1 via MFMA gather-GEMM; 1 tile/wave ----
__global__ __launch_bounds__(256, 4) void k2(
    const char* __restrict__ h2, const int* __restrict__ fidxP,
    const bf16x8* __restrict__ wB, const float* __restrict__ b2,
    float* __restrict__ h3) {
  int blk = blockIdx.x;                         // 10240 blocks x 4 waves = 40960 tiles
  int b = blk & 7;                              // XCD-pinned batch
  int wave = threadIdx.x >> 6;
  int lane = threadIdx.x & 63;
  int col = lane & 15;
  int odd = (lane >> 5) & 1;
  int tile = (blk >> 3) * 4 + wave;             // 5120 tiles per batch
  const char* hb = h2 + (size_t)b * N1 * 32 + ((lane >> 4) & 1) * 16;

  bf16x8 Bf[10];
#pragma unroll
  for (int i = 0; i < 10; ++i) Bf[i] = wB[i * 64 + lane];
  float bias0 = b2[col];
  float bias1 = b2[16 + col];

  const int* fp = fidxP + ((size_t)tile * 16 + col) * 12 + odd * 6;
  int4 T = *(const int4_u*)fp;                  // 4 taps of my parity
  int  T4 = fp[4];                              // 5th tap
  f32x4 acc0 = {0.f, 0.f, 0.f, 0.f};
  f32x4 acc1 = {0.f, 0.f, 0.f, 0.f};
  bf16x8 A;
  A = *(const bf16x8*)(hb + T.x);
  acc0 = __builtin_amdgcn_mfma_f32_16x16x32_bf16(A, Bf[0], acc0, 0, 0, 0);
  acc1 = __builtin_amdgcn_mfma_f32_16x16x32_bf16(A, Bf[1], acc1, 0, 0, 0);
  A = *(const bf16x8*)(hb + T.y);
  acc0 = __builtin_amdgcn_mfma_f32_16x16x32_bf16(A, Bf[2], acc0, 0, 0, 0);
  acc1 = __builtin_amdgcn_mfma_f32_16x16x32_bf16(A, Bf[3], acc1, 0, 0, 0);
  A = *(const bf16x8*)(hb + T.z);
  acc0 = __builtin_amdgcn_mfma_f32_16x16x32_bf16(A, Bf[4], acc0, 0, 0, 0);
  acc1 = __builtin_amdgcn_mfma_f32_16x16x32_bf16(A, Bf[5], acc1, 0, 0, 0);
  A = *(const bf16x8*)(hb + T.w);
  acc0 = __builtin_amdgcn_mfma_f32_16x16x32_bf16(A, Bf[6], acc0, 0, 0, 0);
  acc1 = __builtin_amdgcn_mfma_f32_16x16x32_bf16(A, Bf[7], acc1, 0, 0, 0);
  A = *(const bf16x8*)(hb + T4);
  acc0 = __builtin_amdgcn_mfma_f32_16x16x32_bf16(A, Bf[8], acc0, 0, 0, 0);
  acc1 = __builtin_amdgcn_mfma_f32_16x16x32_bf16(A, Bf[9], acc1, 0, 0, 0);
  float m0 = fmaxf(fmaxf(acc0[0], acc0[1]), fmaxf(acc0[2], acc0[3])) + bias0;
  float m1 = fmaxf(fmaxf(acc1[0], acc1[1]), fmaxf(acc1[2], acc1[3])) + bias1;
  int j = tile * 4 + (lane >> 4);
  float* dst = h3 + ((size_t)b * N2 + j) * 32 + col;
  dst[0]  = m0;
  dst[16] = m1;
}

// ---- G[b][c][k] = sum_n A[n][k] * h3[b][n][c] : sequential h3 stream ----
#define K3B_NCH 256
__global__ __launch_bounds__(256) void k3b(
    const float* __restrict__ h3, const float* __restrict__ A12,
    float* __restrict__ G) {
  __shared__ float SA[K3B_NCH * 12];
  __shared__ float GL[320];
  int blk = blockIdx.x;                         // 8 b x 80 chunks
  int b = blk & 7;
  int n0 = (blk >> 3) * K3B_NCH;
  int tid = threadIdx.x;
  const float4* src = (const float4*)(A12 + (size_t)n0 * 12);
#pragma unroll
  for (int i = 0; i < 3; ++i)
    ((float4*)SA)[tid + i * 256] = src[tid + i * 256];
  for (int i = tid; i < 320; i += 256) GL[i] = 0.f;
  __syncthreads();
  int wave = tid >> 6, lane = tid & 63;
  int c = lane & 31, nh = lane >> 5;
  float acc[10];
#pragma unroll
  for (int o = 0; o < 10; ++o) acc[o] = 0.f;
#pragma unroll 4
  for (int s = 0; s < K3B_NCH / 8; ++s) {
    int nl = s * 8 + wave * 2 + nh;
    float hv = h3[((size_t)b * N2 + n0 + nl) * 32 + c];
    const float4* ar = (const float4*)(SA + nl * 12);
    float4 a0 = ar[0], a1 = ar[1], a2 = ar[2];
    acc[0] += hv * a0.x; acc[1] += hv * a0.y;
    acc[2] += hv * a0.z; acc[3] += hv * a0.w;
    acc[4] += hv * a1.x; acc[5] += hv * a1.y;
    acc[6] += hv * a1.z; acc[7] += hv * a1.w;
    acc[8] += hv * a2.x; acc[9] += hv * a2.y;
  }
#pragma unroll
  for (int o = 0; o < 10; ++o) acc[o] += __shfl_xor(acc[o], 32);
  if (lane < 32) {
#pragma unroll
    for (int o = 0; o < 10; ++o) atomicAdd(&GL[c * 10 + o], acc[o]);
  }
  __syncthreads();
  for (int i = tid; i < 320; i += 256)
    atomicAdd(&G[b * 320 + i], GL[i]);
}

// ---- out[b][o] += (1/N2) * sum_{c,k} w3t[k][c][o] * G[b][c][k] ----
__global__ __launch_bounds__(256) void k3c(
    const float* __restrict__ G, const float* __restrict__ w3t,
    float* __restrict__ out) {
  int t = blockIdx.x * 256 + threadIdx.x;       // 2560 threads
  int pair = t >> 5, c = t & 31;
  int b = pair / 10, o = pair % 10;
  float s = 0.f;
#pragma unroll
  for (int k = 0; k < KC; ++k)
    s += G[b * 320 + c * 10 + k] * w3t[k * 320 + c * 10 + o];
#pragma unroll
  for (int off = 1; off < 32; off <<= 1) s += __shfl_xor(s, off);
  if ((threadIdx.x & 31) == 0) atomicAdd(&out[pair], s * (1.0f / N2));
}

extern "C" void kernel_launch(void* const* d_in, const int* in_sizes, int n_in,
                              void* d_out, int out_size, void* d_ws, size_t ws_size,
                              hipStream_t stream) {
  const float* x       = (const float*)d_in[0];
  const int*   conv_t0 = (const int*)d_in[1];
  const int*   conv_t1 = (const int*)d_in[2];
  const int*   conv_t2 = (const int*)d_in[3];
  const int*   adj0    = (const int*)d_in[4];
  const int*   adj1    = (const int*)d_in[5];
  const int*   pool0   = (const int*)d_in[6];
  const int*   pool1   = (const int*)d_in[7];
  const float* w1      = (const float*)d_in[8];
  const float* b1      = (const float*)d_in[9];
  const float* w2      = (const float*)d_in[10];
  const float* b2      = (const float*)d_in[11];
  const float* w3      = (const float*)d_in[12];
  const float* b3      = (const float*)d_in[13];
  float* out  = (float*)d_out;
  float* wsf  = (float*)d_ws;

  // words: region0 (xT64 [N0][16w] = 5,242,880 / h3 alias) | h2 5,242,880 |
  // fidxM 3,932,160 | fidxP 983,040 | A12 245,760 | G 2,560 | wB1 512 |
  // wB 2,560 | w3t 3,200  -> ~62.7 MB
  float* h3b   = wsf;
  uint4* xT64  = (uint4*)wsf;                   // aliases h3, dead after k1
  unsigned short* h2b = (unsigned short*)(wsf + 5242880);
  int* fidxM   = (int*)(wsf + 2 * 5242880);
  int* fidxP   = fidxM + (size_t)N1 * 4 * 12;
  float* A12   = (float*)(fidxP + (size_t)N2 * 4 * 12);
  float* G     = A12 + (size_t)N2 * 12;
  unsigned short* wB1 = (unsigned short*)(G + 2560);
  unsigned short* wB  = wB1 + 1024;
  float* w3t   = (float*)(wB + 5120);

  hipMemsetAsync(A12, 0, (size_t)(N2 * 12 + 2560) * 4, stream);  // A12 + G
  kpre<<<3380, 256, 0, stream>>>(x, xT64, conv_t0, conv_t1, conv_t2,
                                 adj0, adj1, pool0, pool1,
                                 fidxM, fidxP, A12,
                                 w1, w2, w3, b3, wB1, wB, w3t, out);
  k1<<<5120, 256, 0, stream>>>((const char*)xT64, fidxM, (const bf16x8*)wB1, b1, h2b);
  k2<<<10240, 256, 0, stream>>>((const char*)h2b, fidxP, (const bf16x8*)wB, b2, h3b);
  k3b<<<8 * (N2 / K3B_NCH), 256, 0, stream>>>(h3b, A12, G);
  k3c<<<10, 256, 0, stream>>>(G, w3t, out);
}

// Round 16
// 147.113 us; speedup vs baseline: 1.2383x; 1.2383x over previous
//
#include <hip/hip_runtime.h>

#define NB 8
#define CIN 3
#define N0 327680
#define N1 81920
#define N2 20480
#define KC 10
#define KA 4

typedef __attribute__((ext_vector_type(8))) short bf16x8;
typedef __attribute__((ext_vector_type(4))) float f32x4;
typedef int4  __attribute__((aligned(4))) int4_u;

__device__ __forceinline__ unsigned f2bf(float f) {          // RNE float->bf16
  unsigned u = __float_as_uint(f);
  return (u + 0x7FFFu + ((u >> 16) & 1u)) >> 16;
}

union bfrag { bf16x8 v; unsigned u[4]; };

// ---- fused prep: blocks [0,1280) transx | [1280,2560) fidx | [2560,3360) hist |
// [3360,3380) weight-prep.  A12/G zeroed by hipMemsetAsync beforehand. ----
__global__ __launch_bounds__(256) void kpre(
    const float* __restrict__ x, uint4* __restrict__ xT64,
    const int* __restrict__ conv_t0, const int* __restrict__ conv_t1,
    const int* __restrict__ conv_t2,
    const int* __restrict__ adj0, const int* __restrict__ adj1,
    const int* __restrict__ pool0, const int* __restrict__ pool1,
    int* __restrict__ fidxM, int* __restrict__ fidxP, float* __restrict__ A12,
    const float* __restrict__ w1, const float* __restrict__ w2,
    const float* __restrict__ w3, const float* __restrict__ b3,
    unsigned short* __restrict__ wB1, unsigned short* __restrict__ wB,
    float* __restrict__ w3t, float* __restrict__ out) {
  int blk = blockIdx.x;
  if (blk < 1280) {
    // ---- x -> xT64 [n][64B]: 4 bpair-triples {c0|c1, c2|c0', c1'|c2'} + 16B pad ----
    int n = blk * 256 + threadIdx.x;
    unsigned d[12];
#pragma unroll
    for (int bp = 0; bp < 4; ++bp) {
      const float* pe = x + (size_t)(2 * bp) * CIN * N0 + n;       // even batch
      const float* po = pe + (size_t)CIN * N0;                    // odd batch
      float e0 = pe[0], e1 = pe[N0], e2 = pe[2 * N0];
      float o0 = po[0], o1 = po[N0], o2 = po[2 * N0];
      d[bp * 3 + 0] = f2bf(e0) | (f2bf(e1) << 16);
      d[bp * 3 + 1] = f2bf(e2) | (f2bf(o0) << 16);
      d[bp * 3 + 2] = f2bf(o1) | (f2bf(o2) << 16);
    }
    uint4* dst = xT64 + (size_t)n * 4;
    dst[0] = make_uint4(d[0], d[1], d[2], d[3]);
    dst[1] = make_uint4(d[4], d[5], d[6], d[7]);
    dst[2] = make_uint4(d[8], d[9], d[10], d[11]);
    dst[3] = make_uint4(0, 0, 0, 0);
  } else if (blk < 2560) {
    // ---- index tables ----
    // fidxM row (48B): [t0 t1 t8 t9 | t2 t3 t4 t5 | t6 t7 0 0]  (byte offs, x64)
    // fidxP row (48B): [e0 e2 e4 e6 | e8 0 o1 o3 | o5 o7 o9 0]  (byte offs, x32)
    int t = (blk - 1280) * 256 + threadIdx.x;   // N1*4 threads
    int j = t >> 2, p = t & 3;
    int pj = pool0[j];
    int pos = adj0[pj * KA + p];
    const int2* s0 = (const int2*)(conv_t0 + (size_t)pos * 10);
    int2 q0 = s0[0], q1 = s0[1], q2 = s0[2], q3 = s0[3], q4 = s0[4];
    int4_u* dM = (int4_u*)(fidxM + (size_t)t * 12);
    dM[0] = make_int4(q0.x * 64, q0.y * 64, q4.x * 64, q4.y * 64);
    dM[1] = make_int4(q1.x * 64, q1.y * 64, q2.x * 64, q2.y * 64);
    dM[2] = make_int4(q3.x * 64, q3.y * 64, 0, 0);
    if (j < N2) {
      int qj = pool1[j];
      int qos = adj1[qj * KA + p];
      const int2* s1 = (const int2*)(conv_t1 + (size_t)qos * 10);
      int2 r0 = s1[0], r1 = s1[1], r2 = s1[2], r3 = s1[3], r4 = s1[4];
      int4_u* dP = (int4_u*)(fidxP + (size_t)t * 12);
      dP[0] = make_int4(r0.x * 32, r1.x * 32, r2.x * 32, r3.x * 32);
      dP[1] = make_int4(r4.x * 32, 0,          r0.y * 32, r1.y * 32);
      dP[2] = make_int4(r2.y * 32, r3.y * 32, r4.y * 32, 0);
    }
  } else if (blk < 3360) {
    // ---- histogram A[n][k] = #{j: conv_t2[j,k] = n} ----
    int t = (blk - 2560) * 256 + threadIdx.x;   // N2*10 threads
    int n = conv_t2[t];
    int k = t % 10;
    atomicAdd(&A12[n * 12 + k], 1.0f);
  } else {
    // ---- weight prep ----
    int t = (blk - 3360) * 256 + threadIdx.x;
    if (t < 1024) {
      int ch = t >> 9, rest = t & 511, l = rest >> 3, e = rest & 7;
      int k = ch * 32 + ((l >> 4) * 8) + e;
      int tap = k >> 2, cc = k & 3;
      float v = (tap < KC && cc < CIN) ? w1[((l & 15) * CIN + cc) * KC + tap] : 0.f;
      wB1[t] = (unsigned short)f2bf(v);
    }
    if (t < 5120) {
      int e = t & 7, l = (t >> 3) & 63, nt = (t >> 9) & 1, q = t >> 10;
      int kc = q * 32 + ((l >> 4) * 8) + e;
      int tap = kc >> 4, c = kc & 15;
      int o = nt * 16 + (l & 15);
      wB[t] = (unsigned short)f2bf(w2[(o * 16 + c) * KC + tap]);
    }
    if (t < 3200) { int o = t % 10, r = t / 10, c = r & 31, k = r >> 5;
                    w3t[t] = w3[(o * 32 + c) * KC + k]; }
    if (t < 80)   out[t] = b3[t % 10];
  }
}

// dword triple of bpair s (s compile-time) from a 12-dword row (Ra,Rb,Rc)
#define TR0(s) ((s) == 0 ? Ra.x : (s) == 1 ? Ra.w : (s) == 2 ? Rb.z : Rc.y)
#define TR1(s) ((s) == 0 ? Ra.y : (s) == 1 ? Rb.x : (s) == 2 ? Rb.w : Rc.z)
#define TR2(s) ((s) == 0 ? Ra.z : (s) == 1 ? Rb.y : (s) == 2 ? Rc.x : Rc.w)

// ---- conv1 (3->16) + maxpool0 via MFMA gather-GEMM. 1 tile/wave; (256,4):
// VGPR cap 128 (uses ~40, no spill) — (256,8) spilled and regressed 53->93 us. ----
__global__ __launch_bounds__(256, 4) void k1(
    const char* __restrict__ xT64, const int* __restrict__ fidxM,
    const bf16x8* __restrict__ wB1, const float* __restrict__ b1,
    unsigned short* __restrict__ h2) {
  int blk = blockIdx.x;                         // 5120 blocks x 4 waves = 20480 tiles
  int wave = threadIdx.x >> 6;
  int lane = threadIdx.x & 63;
  int col = lane & 15, hi = lane >> 4;
  int tile = blk * 4 + wave;
  bf16x8 B0 = wB1[lane];
  bf16x8 B1 = wB1[64 + lane];
  float bias = b1[col];
  int seloff = ((hi + 1) >> 1) << 2;            // ints: hi->{0,4,4,8}

  int4 I = *(const int4_u*)(fidxM + ((size_t)tile * 16 + col) * 12 + seloff);
  int a0 = (hi == 2) ? I.z : I.x;               // tap 2hi
  int a1 = (hi == 2) ? I.w : I.y;               // tap 2hi+1
  const uint4* r0p = (const uint4*)(xT64 + a0);
  const uint4* r1p = (const uint4*)(xT64 + a1);
  uint4 R0a = r0p[0], R0b = r0p[1], R0c = r0p[2];
  uint4 R1a = r1p[0], R1b = r1p[1], R1c = r1p[2];
  uint4 zz = make_uint4(0, 0, 0, 0);
  uint4 R2a = zz, R2b = zz, R2c = zz, R3a = zz, R3b = zz, R3c = zz;
  if (hi == 0) {                                // taps 8,9 real only for hi=0
    const uint4* r2p = (const uint4*)(xT64 + I.z);
    const uint4* r3p = (const uint4*)(xT64 + I.w);
    R2a = r2p[0]; R2b = r2p[1]; R2c = r2p[2];
    R3a = r3p[0]; R3b = r3p[1]; R3c = r3p[2];
  }
  size_t j = (size_t)tile * 4 + hi;
  unsigned short* dst = h2 + j * 16 + col;

#define DO_BPAIR(s)                                                           \
  {                                                                           \
    unsigned t0, t1, t2, u0, u1, u2, v0, v1, v2, w0, w1, w2;                  \
    { uint4 Ra = R0a, Rb = R0b, Rc = R0c;                                     \
      t0 = TR0(s); t1 = TR1(s); t2 = TR2(s); }                                \
    { uint4 Ra = R1a, Rb = R1b, Rc = R1c;                                     \
      u0 = TR0(s); u1 = TR1(s); u2 = TR2(s); }                                \
    { uint4 Ra = R2a, Rb = R2b, Rc = R2c;                                     \
      v0 = TR0(s); v1 = TR1(s); v2 = TR2(s); }                                \
    { uint4 Ra = R3a, Rb = R3b, Rc = R3c;                                     \
      w0 = TR0(s); w1 = TR1(s); w2 = TR2(s); }                                \
    bfrag A0c0, A1c0, A0c1, A1c1;                                             \
    A0c0.u[0] = t0; A0c0.u[1] = t1 & 0xFFFFu;                                 \
    A0c0.u[2] = u0; A0c0.u[3] = u1 & 0xFFFFu;                                 \
    A1c0.u[0] = (t1 >> 16) | (t2 << 16); A1c0.u[1] = t2 >> 16;                \
    A1c0.u[2] = (u1 >> 16) | (u2 << 16); A1c0.u[3] = u2 >> 16;                \
    A0c1.u[0] = v0; A0c1.u[1] = v1 & 0xFFFFu;                                 \
    A0c1.u[2] = w0; A0c1.u[3] = w1 & 0xFFFFu;                                 \
    A1c1.u[0] = (v1 >> 16) | (v2 << 16); A1c1.u[1] = v2 >> 16;                \
    A1c1.u[2] = (w1 >> 16) | (w2 << 16); A1c1.u[3] = w2 >> 16;                \
    f32x4 z = {0.f, 0.f, 0.f, 0.f};                                           \
    f32x4 acc0 = __builtin_amdgcn_mfma_f32_16x16x32_bf16(A0c0.v, B0, z, 0, 0, 0); \
    acc0 = __builtin_amdgcn_mfma_f32_16x16x32_bf16(A0c1.v, B1, acc0, 0, 0, 0);    \
    f32x4 acc1 = __builtin_amdgcn_mfma_f32_16x16x32_bf16(A1c0.v, B0, z, 0, 0, 0); \
    acc1 = __builtin_amdgcn_mfma_f32_16x16x32_bf16(A1c1.v, B1, acc1, 0, 0, 0);    \
    float m0 = fmaxf(fmaxf(acc0[0], acc0[1]), fmaxf(acc0[2], acc0[3])) + bias;    \
    float m1 = fmaxf(fmaxf(acc1[0], acc1[1]), fmaxf(acc1[2], acc1[3])) + bias;    \
    dst[(size_t)(2 * (s)) * N1 * 16]     = (unsigned short)f2bf(m0);          \
    dst[(size_t)(2 * (s) + 1) * N1 * 16] = (unsigned short)f2bf(m1);          \
  }
  DO_BPAIR(0)
  DO_BPAIR(1)
  DO_BPAIR(2)
  DO_BPAIR(3)
#undef DO_BPAIR
}

// ---- conv2 (16->32) + maxpool1 via MFMA gather-GEMM; 1 tile/wave ----
__global__ __launch_bounds__(256, 4) void k2(
    const char* __restrict__ h2, const int* __restrict__ fidxP,
    const bf16x8* __restrict__ wB, const float* __restrict__ b2,
    float* __restrict__ h3) {
  int blk = blockIdx.x;                         // 10240 blocks x 4 waves = 40960 tiles
  int b = blk & 7;                              // XCD-pinned batch
  int wave = threadIdx.x >> 6;
  int lane = threadIdx.x & 63;
  int col = lane & 15;
  int odd = (lane >> 5) & 1;
  int tile = (blk >> 3) * 4 + wave;             // 5120 tiles per batch
  const char* hb = h2 + (size_t)b * N1 * 32 + ((lane >> 4) & 1) * 16;

  bf16x8 Bf[10];
#pragma unroll
  for (int i = 0; i < 10; ++i) Bf[i] = wB[i * 64 + lane];
  float bias0 = b2[col];
  float bias1 = b2[16 + col];

  const int* fp = fidxP + ((size_t)tile * 16 + col) * 12 + odd * 6;
  int4 T = *(const int4_u*)fp;                  // 4 taps of my parity
  int  T4 = fp[4];                              // 5th tap
  f32x4 acc0 = {0.f, 0.f, 0.f, 0.f};
  f32x4 acc1 = {0.f, 0.f, 0.f, 0.f};
  bf16x8 A;
  A = *(const bf16x8*)(hb + T.x);
  acc0 = __builtin_amdgcn_mfma_f32_16x16x32_bf16(A, Bf[0], acc0, 0, 0, 0);
  acc1 = __builtin_amdgcn_mfma_f32_16x16x32_bf16(A, Bf[1], acc1, 0, 0, 0);
  A = *(const bf16x8*)(hb + T.y);
  acc0 = __builtin_amdgcn_mfma_f32_16x16x32_bf16(A, Bf[2], acc0, 0, 0, 0);
  acc1 = __builtin_amdgcn_mfma_f32_16x16x32_bf16(A, Bf[3], acc1, 0, 0, 0);
  A = *(const bf16x8*)(hb + T.z);
  acc0 = __builtin_amdgcn_mfma_f32_16x16x32_bf16(A, Bf[4], acc0, 0, 0, 0);
  acc1 = __builtin_amdgcn_mfma_f32_16x16x32_bf16(A, Bf[5], acc1, 0, 0, 0);
  A = *(const bf16x8*)(hb + T.w);
  acc0 = __builtin_amdgcn_mfma_f32_16x16x32_bf16(A, Bf[6], acc0, 0, 0, 0);
  acc1 = __builtin_amdgcn_mfma_f32_16x16x32_bf16(A, Bf[7], acc1, 0, 0, 0);
  A = *(const bf16x8*)(hb + T4);
  acc0 = __builtin_amdgcn_mfma_f32_16x16x32_bf16(A, Bf[8], acc0, 0, 0, 0);
  acc1 = __builtin_amdgcn_mfma_f32_16x16x32_bf16(A, Bf[9], acc1, 0, 0, 0);
  float m0 = fmaxf(fmaxf(acc0[0], acc0[1]), fmaxf(acc0[2], acc0[3])) + bias0;
  float m1 = fmaxf(fmaxf(acc1[0], acc1[1]), fmaxf(acc1[2], acc1[3])) + bias1;
  int j = tile * 4 + (lane >> 4);
  float* dst = h3 + ((size_t)b * N2 + j) * 32 + col;
  dst[0]  = m0;
  dst[16] = m1;
}

// ---- G[b][c][k] = sum_n A[n][k] * h3[b][n][c] : sequential h3 stream ----
#define K3B_NCH 256
__global__ __launch_bounds__(256) void k3b(
    const float* __restrict__ h3, const float* __restrict__ A12,
    float* __restrict__ G) {
  __shared__ float SA[K3B_NCH * 12];
  __shared__ float GL[320];
  int blk = blockIdx.x;                         // 8 b x 80 chunks
  int b = blk & 7;
  int n0 = (blk >> 3) * K3B_NCH;
  int tid = threadIdx.x;
  const float4* src = (const float4*)(A12 + (size_t)n0 * 12);
#pragma unroll
  for (int i = 0; i < 3; ++i)
    ((float4*)SA)[tid + i * 256] = src[tid + i * 256];
  for (int i = tid; i < 320; i += 256) GL[i] = 0.f;
  __syncthreads();
  int wave = tid >> 6, lane = tid & 63;
  int c = lane & 31, nh = lane >> 5;
  float acc[10];
#pragma unroll
  for (int o = 0; o < 10; ++o) acc[o] = 0.f;
#pragma unroll 4
  for (int s = 0; s < K3B_NCH / 8; ++s) {
    int nl = s * 8 + wave * 2 + nh;
    float hv = h3[((size_t)b * N2 + n0 + nl) * 32 + c];
    const float4* ar = (const float4*)(SA + nl * 12);
    float4 a0 = ar[0], a1 = ar[1], a2 = ar[2];
    acc[0] += hv * a0.x; acc[1] += hv * a0.y;
    acc[2] += hv * a0.z; acc[3] += hv * a0.w;
    acc[4] += hv * a1.x; acc[5] += hv * a1.y;
    acc[6] += hv * a1.z; acc[7] += hv * a1.w;
    acc[8] += hv * a2.x; acc[9] += hv * a2.y;
  }
#pragma unroll
  for (int o = 0; o < 10; ++o) acc[o] += __shfl_xor(acc[o], 32);
  if (lane < 32) {
#pragma unroll
    for (int o = 0; o < 10; ++o) atomicAdd(&GL[c * 10 + o], acc[o]);
  }
  __syncthreads();
  for (int i = tid; i < 320; i += 256)
    atomicAdd(&G[b * 320 + i], GL[i]);
}

// ---- out[b][o] += (1/N2) * sum_{c,k} w3t[k][c][o] * G[b][c][k] ----
__global__ __launch_bounds__(256) void k3c(
    const float* __restrict__ G, const float* __restrict__ w3t,
    float* __restrict__ out) {
  int t = blockIdx.x * 256 + threadIdx.x;       // 2560 threads
  int pair = t >> 5, c = t & 31;
  int b = pair / 10, o = pair % 10;
  float s = 0.f;
#pragma unroll
  for (int k = 0; k < KC; ++k)
    s += G[b * 320 + c * 10 + k] * w3t[k * 320 + c * 10 + o];
#pragma unroll
  for (int off = 1; off < 32; off <<= 1) s += __shfl_xor(s, off);
  if ((threadIdx.x & 31) == 0) atomicAdd(&out[pair], s * (1.0f / N2));
}

extern "C" void kernel_launch(void* const* d_in, const int* in_sizes, int n_in,
                              void* d_out, int out_size, void* d_ws, size_t ws_size,
                              hipStream_t stream) {
  const float* x       = (const float*)d_in[0];
  const int*   conv_t0 = (const int*)d_in[1];
  const int*   conv_t1 = (const int*)d_in[2];
  const int*   conv_t2 = (const int*)d_in[3];
  const int*   adj0    = (const int*)d_in[4];
  const int*   adj1    = (const int*)d_in[5];
  const int*   pool0   = (const int*)d_in[6];
  const int*   pool1   = (const int*)d_in[7];
  const float* w1      = (const float*)d_in[8];
  const float* b1      = (const float*)d_in[9];
  const float* w2      = (const float*)d_in[10];
  const float* b2      = (const float*)d_in[11];
  const float* w3      = (const float*)d_in[12];
  const float* b3      = (const float*)d_in[13];
  float* out  = (float*)d_out;
  float* wsf  = (float*)d_ws;

  // words: region0 (xT64 [N0][16w] = 5,242,880 / h3 alias) | h2 5,242,880 |
  // fidxM 3,932,160 | fidxP 983,040 | A12 245,760 | G 2,560 | wB1 512 |
  // wB 2,560 | w3t 3,200  -> ~62.7 MB
  float* h3b   = wsf;
  uint4* xT64  = (uint4*)wsf;                   // aliases h3, dead after k1
  unsigned short* h2b = (unsigned short*)(wsf + 5242880);
  int* fidxM   = (int*)(wsf + 2 * 5242880);
  int* fidxP   = fidxM + (size_t)N1 * 4 * 12;
  float* A12   = (float*)(fidxP + (size_t)N2 * 4 * 12);
  float* G     = A12 + (size_t)N2 * 12;
  unsigned short* wB1 = (unsigned short*)(G + 2560);
  unsigned short* wB  = wB1 + 1024;
  float* w3t   = (float*)(wB + 5120);

  hipMemsetAsync(A12, 0, (size_t)(N2 * 12 + 2560) * 4, stream);  // A12 + G
  kpre<<<3380, 256, 0, stream>>>(x, xT64, conv_t0, conv_t1, conv_t2,
                                 adj0, adj1, pool0, pool1,
                                 fidxM, fidxP, A12,
                                 w1, w2, w3, b3, wB1, wB, w3t, out);
  k1<<<5120, 256, 0, stream>>>((const char*)xT64, fidxM, (const bf16x8*)wB1, b1, h2b);
  k2<<<10240, 256, 0, stream>>>((const char*)h2b, fidxP, (const bf16x8*)wB, b2, h3b);
  k3b<<<8 * (N2 / K3B_NCH), 256, 0, stream>>>(h3b, A12, G);
  k3c<<<10, 256, 0, stream>>>(G, w3t, out);
}

// Round 17
// 144.377 us; speedup vs baseline: 1.2618x; 1.0190x over previous
//
#include <hip/hip_runtime.h>

#define NB 8
#define CIN 3
#define N0 327680
#define N1 81920
#define N2 20480
#define KC 10
#define KA 4

typedef __attribute__((ext_vector_type(8))) short bf16x8;
typedef __attribute__((ext_vector_type(4))) float f32x4;
typedef int4  __attribute__((aligned(4))) int4_u;

__device__ __forceinline__ unsigned f2bf(float f) {          // RNE float->bf16
  unsigned u = __float_as_uint(f);
  return (u + 0x7FFFu + ((u >> 16) & 1u)) >> 16;
}

union bfrag { bf16x8 v; unsigned u[4]; };

// ---- fused prep: blocks [0,1280) transx | [1280,2560) fidx | [2560,3360) hist |
// [3360,3380) weight-prep.  A12/G zeroed by hipMemsetAsync beforehand. ----
__global__ __launch_bounds__(256) void kpre(
    const float* __restrict__ x, uint4* __restrict__ xT64,
    const int* __restrict__ conv_t0, const int* __restrict__ conv_t1,
    const int* __restrict__ conv_t2,
    const int* __restrict__ adj0, const int* __restrict__ adj1,
    const int* __restrict__ pool0, const int* __restrict__ pool1,
    int* __restrict__ fidxM, int* __restrict__ fidxP, float* __restrict__ A12,
    const float* __restrict__ w1, const float* __restrict__ w2,
    const float* __restrict__ w3, const float* __restrict__ b3,
    unsigned short* __restrict__ wB1, unsigned short* __restrict__ wB,
    float* __restrict__ w3t, float* __restrict__ out) {
  int blk = blockIdx.x;
  if (blk < 1280) {
    // ---- x -> xT64 [n][64B]: 4 bpair-triples {c0|c1, c2|c0', c1'|c2'} + 16B pad ----
    int n = blk * 256 + threadIdx.x;
    unsigned d[12];
#pragma unroll
    for (int bp = 0; bp < 4; ++bp) {
      const float* pe = x + (size_t)(2 * bp) * CIN * N0 + n;       // even batch
      const float* po = pe + (size_t)CIN * N0;                    // odd batch
      float e0 = pe[0], e1 = pe[N0], e2 = pe[2 * N0];
      float o0 = po[0], o1 = po[N0], o2 = po[2 * N0];
      d[bp * 3 + 0] = f2bf(e0) | (f2bf(e1) << 16);
      d[bp * 3 + 1] = f2bf(e2) | (f2bf(o0) << 16);
      d[bp * 3 + 2] = f2bf(o1) | (f2bf(o2) << 16);
    }
    uint4* dst = xT64 + (size_t)n * 4;
    dst[0] = make_uint4(d[0], d[1], d[2], d[3]);
    dst[1] = make_uint4(d[4], d[5], d[6], d[7]);
    dst[2] = make_uint4(d[8], d[9], d[10], d[11]);
    dst[3] = make_uint4(0, 0, 0, 0);
  } else if (blk < 2560) {
    // ---- index tables, 64B-aligned rows (stride 16 ints) ----
    // fidxM row: [t0 t1 t8 t9 | t2 t3 t4 t5 | t6 t7 0 0 | 0 0 0 0] (byte offs x64)
    // fidxP row: [e0 e2 e4 e6 | e8 0 o1 o3 | o5 o7 o9 0 | 0 0 0 0] (byte offs x32)
    int t = (blk - 1280) * 256 + threadIdx.x;   // N1*4 threads
    int j = t >> 2, p = t & 3;
    int pj = pool0[j];
    int pos = adj0[pj * KA + p];
    const int2* s0 = (const int2*)(conv_t0 + (size_t)pos * 10);
    int2 q0 = s0[0], q1 = s0[1], q2 = s0[2], q3 = s0[3], q4 = s0[4];
    int4_u* dM = (int4_u*)(fidxM + (size_t)t * 16);
    dM[0] = make_int4(q0.x * 64, q0.y * 64, q4.x * 64, q4.y * 64);
    dM[1] = make_int4(q1.x * 64, q1.y * 64, q2.x * 64, q2.y * 64);
    dM[2] = make_int4(q3.x * 64, q3.y * 64, 0, 0);
    dM[3] = make_int4(0, 0, 0, 0);
    if (j < N2) {
      int qj = pool1[j];
      int qos = adj1[qj * KA + p];
      const int2* s1 = (const int2*)(conv_t1 + (size_t)qos * 10);
      int2 r0 = s1[0], r1 = s1[1], r2 = s1[2], r3 = s1[3], r4 = s1[4];
      int4_u* dP = (int4_u*)(fidxP + (size_t)t * 16);
      dP[0] = make_int4(r0.x * 32, r1.x * 32, r2.x * 32, r3.x * 32);
      dP[1] = make_int4(r4.x * 32, 0,          r0.y * 32, r1.y * 32);
      dP[2] = make_int4(r2.y * 32, r3.y * 32, r4.y * 32, 0);
      dP[3] = make_int4(0, 0, 0, 0);
    }
  } else if (blk < 3360) {
    // ---- histogram A[n][k] = #{j: conv_t2[j,k] = n} ----
    int t = (blk - 2560) * 256 + threadIdx.x;   // N2*10 threads
    int n = conv_t2[t];
    int k = t % 10;
    atomicAdd(&A12[n * 12 + k], 1.0f);
  } else {
    // ---- weight prep ----
    int t = (blk - 3360) * 256 + threadIdx.x;
    if (t < 1024) {
      int ch = t >> 9, rest = t & 511, l = rest >> 3, e = rest & 7;
      int k = ch * 32 + ((l >> 4) * 8) + e;
      int tap = k >> 2, cc = k & 3;
      float v = (tap < KC && cc < CIN) ? w1[((l & 15) * CIN + cc) * KC + tap] : 0.f;
      wB1[t] = (unsigned short)f2bf(v);
    }
    if (t < 5120) {
      int e = t & 7, l = (t >> 3) & 63, nt = (t >> 9) & 1, q = t >> 10;
      int kc = q * 32 + ((l >> 4) * 8) + e;
      int tap = kc >> 4, c = kc & 15;
      int o = nt * 16 + (l & 15);
      wB[t] = (unsigned short)f2bf(w2[(o * 16 + c) * KC + tap]);
    }
    if (t < 3200) { int o = t % 10, r = t / 10, c = r & 31, k = r >> 5;
                    w3t[t] = w3[(o * 32 + c) * KC + k]; }
    if (t < 80)   out[t] = b3[t % 10];
  }
}

// dword triple of bpair s (s compile-time) from a 12-dword row (Ra,Rb,Rc)
#define TR0(s) ((s) == 0 ? Ra.x : (s) == 1 ? Ra.w : (s) == 2 ? Rb.z : Rc.y)
#define TR1(s) ((s) == 0 ? Ra.y : (s) == 1 ? Rb.x : (s) == 2 ? Rb.w : Rc.z)
#define TR2(s) ((s) == 0 ? Ra.z : (s) == 1 ? Rb.y : (s) == 2 ? Rc.x : Rc.w)

// ---- conv1 (3->16) + maxpool0 via MFMA gather-GEMM. 1 tile/wave; (256,4):
// VGPR cap 128 (uses ~40, no spill) — (256,8) spilled and regressed 53->93 us. ----
__global__ __launch_bounds__(256, 4) void k1(
    const char* __restrict__ xT64, const int* __restrict__ fidxM,
    const bf16x8* __restrict__ wB1, const float* __restrict__ b1,
    unsigned short* __restrict__ h2) {
  int blk = blockIdx.x;                         // 5120 blocks x 4 waves = 20480 tiles
  int wave = threadIdx.x >> 6;
  int lane = threadIdx.x & 63;
  int col = lane & 15, hi = lane >> 4;
  int tile = blk * 4 + wave;
  bf16x8 B0 = wB1[lane];
  bf16x8 B1 = wB1[64 + lane];
  float bias = b1[col];
  int seloff = ((hi + 1) >> 1) << 2;            // ints: hi->{0,4,4,8}

  int4 I = *(const int4_u*)(fidxM + (((size_t)tile * 16 + col) << 4) + seloff);
  int a0 = (hi == 2) ? I.z : I.x;               // tap 2hi
  int a1 = (hi == 2) ? I.w : I.y;               // tap 2hi+1
  const uint4* r0p = (const uint4*)(xT64 + a0);
  const uint4* r1p = (const uint4*)(xT64 + a1);
  uint4 R0a = r0p[0], R0b = r0p[1], R0c = r0p[2];
  uint4 R1a = r1p[0], R1b = r1p[1], R1c = r1p[2];
  uint4 zz = make_uint4(0, 0, 0, 0);
  uint4 R2a = zz, R2b = zz, R2c = zz, R3a = zz, R3b = zz, R3c = zz;
  if (hi == 0) {                                // taps 8,9 real only for hi=0
    const uint4* r2p = (const uint4*)(xT64 + I.z);
    const uint4* r3p = (const uint4*)(xT64 + I.w);
    R2a = r2p[0]; R2b = r2p[1]; R2c = r2p[2];
    R3a = r3p[0]; R3b = r3p[1]; R3c = r3p[2];
  }
  size_t j = (size_t)tile * 4 + hi;
  unsigned short* dst = h2 + j * 16 + col;

#define DO_BPAIR(s)                                                           \
  {                                                                           \
    unsigned t0, t1, t2, u0, u1, u2, v0, v1, v2, w0, w1, w2;                  \
    { uint4 Ra = R0a, Rb = R0b, Rc = R0c;                                     \
      t0 = TR0(s); t1 = TR1(s); t2 = TR2(s); }                                \
    { uint4 Ra = R1a, Rb = R1b, Rc = R1c;                                     \
      u0 = TR0(s); u1 = TR1(s); u2 = TR2(s); }                                \
    { uint4 Ra = R2a, Rb = R2b, Rc = R2c;                                     \
      v0 = TR0(s); v1 = TR1(s); v2 = TR2(s); }                                \
    { uint4 Ra = R3a, Rb = R3b, Rc = R3c;                                     \
      w0 = TR0(s); w1 = TR1(s); w2 = TR2(s); }                                \
    bfrag A0c0, A1c0, A0c1, A1c1;                                             \
    A0c0.u[0] = t0; A0c0.u[1] = t1 & 0xFFFFu;                                 \
    A0c0.u[2] = u0; A0c0.u[3] = u1 & 0xFFFFu;                                 \
    A1c0.u[0] = (t1 >> 16) | (t2 << 16); A1c0.u[1] = t2 >> 16;                \
    A1c0.u[2] = (u1 >> 16) | (u2 << 16); A1c0.u[3] = u2 >> 16;                \
    A0c1.u[0] = v0; A0c1.u[1] = v1 & 0xFFFFu;                                 \
    A0c1.u[2] = w0; A0c1.u[3] = w1 & 0xFFFFu;                                 \
    A1c1.u[0] = (v1 >> 16) | (v2 << 16); A1c1.u[1] = v2 >> 16;                \
    A1c1.u[2] = (w1 >> 16) | (w2 << 16); A1c1.u[3] = w2 >> 16;                \
    f32x4 z = {0.f, 0.f, 0.f, 0.f};                                           \
    f32x4 acc0 = __builtin_amdgcn_mfma_f32_16x16x32_bf16(A0c0.v, B0, z, 0, 0, 0); \
    acc0 = __builtin_amdgcn_mfma_f32_16x16x32_bf16(A0c1.v, B1, acc0, 0, 0, 0);    \
    f32x4 acc1 = __builtin_amdgcn_mfma_f32_16x16x32_bf16(A1c0.v, B0, z, 0, 0, 0); \
    acc1 = __builtin_amdgcn_mfma_f32_16x16x32_bf16(A1c1.v, B1, acc1, 0, 0, 0);    \
    float m0 = fmaxf(fmaxf(acc0[0], acc0[1]), fmaxf(acc0[2], acc0[3])) + bias;    \
    float m1 = fmaxf(fmaxf(acc1[0], acc1[1]), fmaxf(acc1[2], acc1[3])) + bias;    \
    dst[(size_t)(2 * (s)) * N1 * 16]     = (unsigned short)f2bf(m0);          \
    dst[(size_t)(2 * (s) + 1) * N1 * 16] = (unsigned short)f2bf(m1);          \
  }
  DO_BPAIR(0)
  DO_BPAIR(1)
  DO_BPAIR(2)
  DO_BPAIR(3)
#undef DO_BPAIR
}

// ---- conv2 (16->32) + maxpool1 via MFMA gather-GEMM; 8 tiles/wave (R13-proven:
// Bf[10] preload amortized over 8 tiles; unroll-2 pipelines idx under MFMA) ----
__global__ __launch_bounds__(256, 4) void k2(
    const char* __restrict__ h2, const int* __restrict__ fidxP,
    const bf16x8* __restrict__ wB, const float* __restrict__ b2,
    float* __restrict__ h3) {
  int blk = blockIdx.x;                         // 1280 blocks
  int b = blk & 7;                              // XCD-pinned batch
  int wave = threadIdx.x >> 6;
  int lane = threadIdx.x & 63;
  int col = lane & 15;
  int odd = (lane >> 5) & 1;
  int tile0 = ((blk >> 3) * 4 + wave) * 8;      // 5120 tiles per batch
  const char* hb = h2 + (size_t)b * N1 * 32 + ((lane >> 4) & 1) * 16;

  bf16x8 Bf[10];
#pragma unroll
  for (int i = 0; i < 10; ++i) Bf[i] = wB[i * 64 + lane];
  float bias0 = b2[col];
  float bias1 = b2[16 + col];

#pragma unroll 2
  for (int i = 0; i < 8; ++i) {
    int tile = tile0 + i;
    const int* fp = fidxP + (((size_t)tile * 16 + col) << 4) + odd * 6;
    int4 T = *(const int4_u*)fp;                // 4 taps of my parity
    int  T4 = fp[4];                            // 5th tap
    f32x4 acc0 = {0.f, 0.f, 0.f, 0.f};
    f32x4 acc1 = {0.f, 0.f, 0.f, 0.f};
    bf16x8 A;
    A = *(const bf16x8*)(hb + T.x);
    acc0 = __builtin_amdgcn_mfma_f32_16x16x32_bf16(A, Bf[0], acc0, 0, 0, 0);
    acc1 = __builtin_amdgcn_mfma_f32_16x16x32_bf16(A, Bf[1], acc1, 0, 0, 0);
    A = *(const bf16x8*)(hb + T.y);
    acc0 = __builtin_amdgcn_mfma_f32_16x16x32_bf16(A, Bf[2], acc0, 0, 0, 0);
    acc1 = __builtin_amdgcn_mfma_f32_16x16x32_bf16(A, Bf[3], acc1, 0, 0, 0);
    A = *(const bf16x8*)(hb + T.z);
    acc0 = __builtin_amdgcn_mfma_f32_16x16x32_bf16(A, Bf[4], acc0, 0, 0, 0);
    acc1 = __builtin_amdgcn_mfma_f32_16x16x32_bf16(A, Bf[5], acc1, 0, 0, 0);
    A = *(const bf16x8*)(hb + T.w);
    acc0 = __builtin_amdgcn_mfma_f32_16x16x32_bf16(A, Bf[6], acc0, 0, 0, 0);
    acc1 = __builtin_amdgcn_mfma_f32_16x16x32_bf16(A, Bf[7], acc1, 0, 0, 0);
    A = *(const bf16x8*)(hb + T4);
    acc0 = __builtin_amdgcn_mfma_f32_16x16x32_bf16(A, Bf[8], acc0, 0, 0, 0);
    acc1 = __builtin_amdgcn_mfma_f32_16x16x32_bf16(A, Bf[9], acc1, 0, 0, 0);
    float m0 = fmaxf(fmaxf(acc0[0], acc0[1]), fmaxf(acc0[2], acc0[3])) + bias0;
    float m1 = fmaxf(fmaxf(acc1[0], acc1[1]), fmaxf(acc1[2], acc1[3])) + bias1;
    int j = tile * 4 + (lane >> 4);
    float* dst = h3 + ((size_t)b * N2 + j) * 32 + col;
    dst[0]  = m0;
    dst[16] = m1;
  }
}

// ---- G[b][c][k] = sum_n A[n][k] * h3[b][n][c] : sequential h3 stream ----
#define K3B_NCH 256
__global__ __launch_bounds__(256) void k3b(
    const float* __restrict__ h3, const float* __restrict__ A12,
    float* __restrict__ G) {
  __shared__ float SA[K3B_NCH * 12];
  __shared__ float GL[320];
  int blk = blockIdx.x;                         // 8 b x 80 chunks
  int b = blk & 7;
  int n0 = (blk >> 3) * K3B_NCH;
  int tid = threadIdx.x;
  const float4* src = (const float4*)(A12 + (size_t)n0 * 12);
#pragma unroll
  for (int i = 0; i < 3; ++i)
    ((float4*)SA)[tid + i * 256] = src[tid + i * 256];
  for (int i = tid; i < 320; i += 256) GL[i] = 0.f;
  __syncthreads();
  int wave = tid >> 6, lane = tid & 63;
  int c = lane & 31, nh = lane >> 5;
  float acc[10];
#pragma unroll
  for (int o = 0; o < 10; ++o) acc[o] = 0.f;
#pragma unroll 4
  for (int s = 0; s < K3B_NCH / 8; ++s) {
    int nl = s * 8 + wave * 2 + nh;
    float hv = h3[((size_t)b * N2 + n0 + nl) * 32 + c];
    const float4* ar = (const float4*)(SA + nl * 12);
    float4 a0 = ar[0], a1 = ar[1], a2 = ar[2];
    acc[0] += hv * a0.x; acc[1] += hv * a0.y;
    acc[2] += hv * a0.z; acc[3] += hv * a0.w;
    acc[4] += hv * a1.x; acc[5] += hv * a1.y;
    acc[6] += hv * a1.z; acc[7] += hv * a1.w;
    acc[8] += hv * a2.x; acc[9] += hv * a2.y;
  }
#pragma unroll
  for (int o = 0; o < 10; ++o) acc[o] += __shfl_xor(acc[o], 32);
  if (lane < 32) {
#pragma unroll
    for (int o = 0; o < 10; ++o) atomicAdd(&GL[c * 10 + o], acc[o]);
  }
  __syncthreads();
  for (int i = tid; i < 320; i += 256)
    atomicAdd(&G[b * 320 + i], GL[i]);
}

// ---- out[b][o] += (1/N2) * sum_{c,k} w3t[k][c][o] * G[b][c][k] ----
__global__ __launch_bounds__(256) void k3c(
    const float* __restrict__ G, const float* __restrict__ w3t,
    float* __restrict__ out) {
  int t = blockIdx.x * 256 + threadIdx.x;       // 2560 threads
  int pair = t >> 5, c = t & 31;
  int b = pair / 10, o = pair % 10;
  float s = 0.f;
#pragma unroll
  for (int k = 0; k < KC; ++k)
    s += G[b * 320 + c * 10 + k] * w3t[k * 320 + c * 10 + o];
#pragma unroll
  for (int off = 1; off < 32; off <<= 1) s += __shfl_xor(s, off);
  if ((threadIdx.x & 31) == 0) atomicAdd(&out[pair], s * (1.0f / N2));
}

extern "C" void kernel_launch(void* const* d_in, const int* in_sizes, int n_in,
                              void* d_out, int out_size, void* d_ws, size_t ws_size,
                              hipStream_t stream) {
  const float* x       = (const float*)d_in[0];
  const int*   conv_t0 = (const int*)d_in[1];
  const int*   conv_t1 = (const int*)d_in[2];
  const int*   conv_t2 = (const int*)d_in[3];
  const int*   adj0    = (const int*)d_in[4];
  const int*   adj1    = (const int*)d_in[5];
  const int*   pool0   = (const int*)d_in[6];
  const int*   pool1   = (const int*)d_in[7];
  const float* w1      = (const float*)d_in[8];
  const float* b1      = (const float*)d_in[9];
  const float* w2      = (const float*)d_in[10];
  const float* b2      = (const float*)d_in[11];
  const float* w3      = (const float*)d_in[12];
  const float* b3      = (const float*)d_in[13];
  float* out  = (float*)d_out;
  float* wsf  = (float*)d_ws;

  // words: region0 (xT64/h3 alias) 5,242,880 | h2 5,242,880 | fidxM 5,242,880 |
  // fidxP 1,310,720 | A12 245,760 | G 2,560 | wB1 512 | wB 2,560 | w3t 3,200
  // -> ~69.2 MB (R1 proved >= 89.8 MB available)
  float* h3b   = wsf;
  uint4* xT64  = (uint4*)wsf;                   // aliases h3, dead after k1
  unsigned short* h2b = (unsigned short*)(wsf + 5242880);
  int* fidxM   = (int*)(wsf + 2 * 5242880);
  int* fidxP   = fidxM + (size_t)N1 * 4 * 16;
  float* A12   = (float*)(fidxP + (size_t)N2 * 4 * 16);
  float* G     = A12 + (size_t)N2 * 12;
  unsigned short* wB1 = (unsigned short*)(G + 2560);
  unsigned short* wB  = wB1 + 1024;
  float* w3t   = (float*)(wB + 5120);

  hipMemsetAsync(A12, 0, (size_t)(N2 * 12 + 2560) * 4, stream);  // A12 + G
  kpre<<<3380, 256, 0, stream>>>(x, xT64, conv_t0, conv_t1, conv_t2,
                                 adj0, adj1, pool0, pool1,
                                 fidxM, fidxP, A12,
                                 w1, w2, w3, b3, wB1, wB, w3t, out);
  k1<<<5120, 256, 0, stream>>>((const char*)xT64, fidxM, (const bf16x8*)wB1, b1, h2b);
  k2<<<1280, 256, 0, stream>>>((const char*)h2b, fidxP, (const bf16x8*)wB, b2, h3b);
  k3b<<<8 * (N2 / K3B_NCH), 256, 0, stream>>>(h3b, A12, G);
  k3c<<<10, 256, 0, stream>>>(G, w3t, out);
}

// Round 18
// 131.885 us; speedup vs baseline: 1.3813x; 1.0947x over previous
//
#include <hip/hip_runtime.h>

#define NB 8
#define CIN 3
#define N0 327680
#define N1 81920
#define N2 20480
#define KC 10
#define KA 4

typedef __attribute__((ext_vector_type(8))) short bf16x8;
typedef __attribute__((ext_vector_type(4))) float f32x4;
typedef int4  __attribute__((aligned(4))) int4_u;

__device__ __forceinline__ unsigned f2bf(float f) {          // RNE float->bf16
  unsigned u = __float_as_uint(f);
  return (u + 0x7FFFu + ((u >> 16) & 1u)) >> 16;
}

union bfrag { bf16x8 v; unsigned u[4]; };

// ---- fused prep: blocks [0,1280) transx | [1280,2560) fidx | [2560,3360) hist |
// [3360,3380) weight-prep.  A12/G zeroed by hipMemsetAsync beforehand. ----
__global__ __launch_bounds__(256) void kpre(
    const float* __restrict__ x, uint4* __restrict__ xT64,
    const int* __restrict__ conv_t0, const int* __restrict__ conv_t1,
    const int* __restrict__ conv_t2,
    const int* __restrict__ adj0, const int* __restrict__ adj1,
    const int* __restrict__ pool0, const int* __restrict__ pool1,
    int* __restrict__ fidxM, int* __restrict__ fidxP, float* __restrict__ A12,
    const float* __restrict__ w1, const float* __restrict__ w2,
    const float* __restrict__ w3, const float* __restrict__ b3,
    unsigned short* __restrict__ wB1, unsigned short* __restrict__ wB,
    float* __restrict__ w3t, float* __restrict__ out) {
  int blk = blockIdx.x;
  if (blk < 1280) {
    // ---- x -> xT64 [n][64B]: 4 bpair-triples {c0|c1, c2|c0', c1'|c2'} + 16B pad ----
    int n = blk * 256 + threadIdx.x;
    unsigned d[12];
#pragma unroll
    for (int bp = 0; bp < 4; ++bp) {
      const float* pe = x + (size_t)(2 * bp) * CIN * N0 + n;       // even batch
      const float* po = pe + (size_t)CIN * N0;                    // odd batch
      float e0 = pe[0], e1 = pe[N0], e2 = pe[2 * N0];
      float o0 = po[0], o1 = po[N0], o2 = po[2 * N0];
      d[bp * 3 + 0] = f2bf(e0) | (f2bf(e1) << 16);
      d[bp * 3 + 1] = f2bf(e2) | (f2bf(o0) << 16);
      d[bp * 3 + 2] = f2bf(o1) | (f2bf(o2) << 16);
    }
    uint4* dst = xT64 + (size_t)n * 4;
    dst[0] = make_uint4(d[0], d[1], d[2], d[3]);
    dst[1] = make_uint4(d[4], d[5], d[6], d[7]);
    dst[2] = make_uint4(d[8], d[9], d[10], d[11]);
    dst[3] = make_uint4(0, 0, 0, 0);
  } else if (blk < 2560) {
    // ---- index tables (stride 12 ints = 48B, R13-proven best) ----
    // fidxM row: [t0 t1 t8 t9 | t2 t3 t4 t5 | t6 t7 0 0]  (byte offs, x64)
    // fidxP row: [e0 e2 e4 e6 | e8 0 o1 o3 | o5 o7 o9 0]  (byte offs, x32)
    int t = (blk - 1280) * 256 + threadIdx.x;   // N1*4 threads
    int j = t >> 2, p = t & 3;
    int pj = pool0[j];
    int pos = adj0[pj * KA + p];
    const int2* s0 = (const int2*)(conv_t0 + (size_t)pos * 10);
    int2 q0 = s0[0], q1 = s0[1], q2 = s0[2], q3 = s0[3], q4 = s0[4];
    int4_u* dM = (int4_u*)(fidxM + (size_t)t * 12);
    dM[0] = make_int4(q0.x * 64, q0.y * 64, q4.x * 64, q4.y * 64);
    dM[1] = make_int4(q1.x * 64, q1.y * 64, q2.x * 64, q2.y * 64);
    dM[2] = make_int4(q3.x * 64, q3.y * 64, 0, 0);
    if (j < N2) {
      int qj = pool1[j];
      int qos = adj1[qj * KA + p];
      const int2* s1 = (const int2*)(conv_t1 + (size_t)qos * 10);
      int2 r0 = s1[0], r1 = s1[1], r2 = s1[2], r3 = s1[3], r4 = s1[4];
      int4_u* dP = (int4_u*)(fidxP + (size_t)t * 12);
      dP[0] = make_int4(r0.x * 32, r1.x * 32, r2.x * 32, r3.x * 32);
      dP[1] = make_int4(r4.x * 32, 0,          r0.y * 32, r1.y * 32);
      dP[2] = make_int4(r2.y * 32, r3.y * 32, r4.y * 32, 0);
    }
  } else if (blk < 3360) {
    // ---- histogram A[n][k] = #{j: conv_t2[j,k] = n} ----
    int t = (blk - 2560) * 256 + threadIdx.x;   // N2*10 threads
    int n = conv_t2[t];
    int k = t % 10;
    atomicAdd(&A12[n * 12 + k], 1.0f);
  } else {
    // ---- weight prep ----
    int t = (blk - 3360) * 256 + threadIdx.x;
    if (t < 1024) {
      int ch = t >> 9, rest = t & 511, l = rest >> 3, e = rest & 7;
      int k = ch * 32 + ((l >> 4) * 8) + e;
      int tap = k >> 2, cc = k & 3;
      float v = (tap < KC && cc < CIN) ? w1[((l & 15) * CIN + cc) * KC + tap] : 0.f;
      wB1[t] = (unsigned short)f2bf(v);
    }
    if (t < 5120) {
      int e = t & 7, l = (t >> 3) & 63, nt = (t >> 9) & 1, q = t >> 10;
      int kc = q * 32 + ((l >> 4) * 8) + e;
      int tap = kc >> 4, c = kc & 15;
      int o = nt * 16 + (l & 15);
      wB[t] = (unsigned short)f2bf(w2[(o * 16 + c) * KC + tap]);
    }
    if (t < 3200) { int o = t % 10, r = t / 10, c = r & 31, k = r >> 5;
                    w3t[t] = w3[(o * 32 + c) * KC + k]; }
    if (t < 80)   out[t] = b3[t % 10];
  }
}

// dword triple of bpair s (s compile-time) from a 12-dword row (Ra,Rb,Rc)
#define TR0(s) ((s) == 0 ? Ra.x : (s) == 1 ? Ra.w : (s) == 2 ? Rb.z : Rc.y)
#define TR1(s) ((s) == 0 ? Ra.y : (s) == 1 ? Rb.x : (s) == 2 ? Rb.w : Rc.z)
#define TR2(s) ((s) == 0 ? Ra.z : (s) == 1 ? Rb.y : (s) == 2 ? Rc.x : Rc.w)

// ---- conv1 (3->16) + maxpool0 via MFMA gather-GEMM. 1 tile/wave; (256,4):
// VGPR cap 128 (uses ~40, no spill) — (256,8) spilled and regressed 53->93 us. ----
__global__ __launch_bounds__(256, 4) void k1(
    const char* __restrict__ xT64, const int* __restrict__ fidxM,
    const bf16x8* __restrict__ wB1, const float* __restrict__ b1,
    unsigned short* __restrict__ h2) {
  int blk = blockIdx.x;                         // 5120 blocks x 4 waves = 20480 tiles
  int wave = threadIdx.x >> 6;
  int lane = threadIdx.x & 63;
  int col = lane & 15, hi = lane >> 4;
  int tile = blk * 4 + wave;
  bf16x8 B0 = wB1[lane];
  bf16x8 B1 = wB1[64 + lane];
  float bias = b1[col];
  int seloff = ((hi + 1) >> 1) << 2;            // ints: hi->{0,4,4,8}

  int4 I = *(const int4_u*)(fidxM + ((size_t)tile * 16 + col) * 12 + seloff);
  int a0 = (hi == 2) ? I.z : I.x;               // tap 2hi
  int a1 = (hi == 2) ? I.w : I.y;               // tap 2hi+1
  const uint4* r0p = (const uint4*)(xT64 + a0);
  const uint4* r1p = (const uint4*)(xT64 + a1);
  uint4 R0a = r0p[0], R0b = r0p[1], R0c = r0p[2];
  uint4 R1a = r1p[0], R1b = r1p[1], R1c = r1p[2];
  uint4 zz = make_uint4(0, 0, 0, 0);
  uint4 R2a = zz, R2b = zz, R2c = zz, R3a = zz, R3b = zz, R3c = zz;
  if (hi == 0) {                                // taps 8,9 real only for hi=0
    const uint4* r2p = (const uint4*)(xT64 + I.z);
    const uint4* r3p = (const uint4*)(xT64 + I.w);
    R2a = r2p[0]; R2b = r2p[1]; R2c = r2p[2];
    R3a = r3p[0]; R3b = r3p[1]; R3c = r3p[2];
  }
  size_t j = (size_t)tile * 4 + hi;
  unsigned short* dst = h2 + j * 16 + col;

#define DO_BPAIR(s)                                                           \
  {                                                                           \
    unsigned t0, t1, t2, u0, u1, u2, v0, v1, v2, w0, w1, w2;                  \
    { uint4 Ra = R0a, Rb = R0b, Rc = R0c;                                     \
      t0 = TR0(s); t1 = TR1(s); t2 = TR2(s); }                                \
    { uint4 Ra = R1a, Rb = R1b, Rc = R1c;                                     \
      u0 = TR0(s); u1 = TR1(s); u2 = TR2(s); }                                \
    { uint4 Ra = R2a, Rb = R2b, Rc = R2c;                                     \
      v0 = TR0(s); v1 = TR1(s); v2 = TR2(s); }                                \
    { uint4 Ra = R3a, Rb = R3b, Rc = R3c;                                     \
      w0 = TR0(s); w1 = TR1(s); w2 = TR2(s); }                                \
    bfrag A0c0, A1c0, A0c1, A1c1;                                             \
    A0c0.u[0] = t0; A0c0.u[1] = t1 & 0xFFFFu;                                 \
    A0c0.u[2] = u0; A0c0.u[3] = u1 & 0xFFFFu;                                 \
    A1c0.u[0] = (t1 >> 16) | (t2 << 16); A1c0.u[1] = t2 >> 16;                \
    A1c0.u[2] = (u1 >> 16) | (u2 << 16); A1c0.u[3] = u2 >> 16;                \
    A0c1.u[0] = v0; A0c1.u[1] = v1 & 0xFFFFu;                                 \
    A0c1.u[2] = w0; A0c1.u[3] = w1 & 0xFFFFu;                                 \
    A1c1.u[0] = (v1 >> 16) | (v2 << 16); A1c1.u[1] = v2 >> 16;                \
    A1c1.u[2] = (w1 >> 16) | (w2 << 16); A1c1.u[3] = w2 >> 16;                \
    f32x4 z = {0.f, 0.f, 0.f, 0.f};                                           \
    f32x4 acc0 = __builtin_amdgcn_mfma_f32_16x16x32_bf16(A0c0.v, B0, z, 0, 0, 0); \
    acc0 = __builtin_amdgcn_mfma_f32_16x16x32_bf16(A0c1.v, B1, acc0, 0, 0, 0);    \
    f32x4 acc1 = __builtin_amdgcn_mfma_f32_16x16x32_bf16(A1c0.v, B0, z, 0, 0, 0); \
    acc1 = __builtin_amdgcn_mfma_f32_16x16x32_bf16(A1c1.v, B1, acc1, 0, 0, 0);    \
    float m0 = fmaxf(fmaxf(acc0[0], acc0[1]), fmaxf(acc0[2], acc0[3])) + bias;    \
    float m1 = fmaxf(fmaxf(acc1[0], acc1[1]), fmaxf(acc1[2], acc1[3])) + bias;    \
    dst[(size_t)(2 * (s)) * N1 * 16]     = (unsigned short)f2bf(m0);          \
    dst[(size_t)(2 * (s) + 1) * N1 * 16] = (unsigned short)f2bf(m1);          \
  }
  DO_BPAIR(0)
  DO_BPAIR(1)
  DO_BPAIR(2)
  DO_BPAIR(3)
#undef DO_BPAIR
}

// ---- conv2 (16->32) + maxpool1 + conv3-mean projection, fused. h3 never
// materialized: m0/m1 (= h3[b][j][c]) are folded into G[b][c][k] += m*A[j][k]
// in-register; G flushed via LDS + one 320-atomic pass per block. ----
__global__ __launch_bounds__(256, 4) void k2(
    const char* __restrict__ h2, const int* __restrict__ fidxP,
    const float* __restrict__ A12, const bf16x8* __restrict__ wB,
    const float* __restrict__ b2, float* __restrict__ G) {
  __shared__ float GL[320];
  int blk = blockIdx.x;                         // 1280 blocks
  int b = blk & 7;                              // XCD-pinned batch
  int wave = threadIdx.x >> 6;
  int lane = threadIdx.x & 63;
  int col = lane & 15;
  int odd = (lane >> 5) & 1;
  int tile0 = ((blk >> 3) * 4 + wave) * 8;      // 5120 tiles per batch
  const char* hb = h2 + (size_t)b * N1 * 32 + ((lane >> 4) & 1) * 16;
  for (int i = threadIdx.x; i < 320; i += 256) GL[i] = 0.f;
  __syncthreads();

  bf16x8 Bf[10];
#pragma unroll
  for (int i = 0; i < 10; ++i) Bf[i] = wB[i * 64 + lane];
  float bias0 = b2[col];
  float bias1 = b2[16 + col];
  float g0[10], g1[10];
#pragma unroll
  for (int k = 0; k < 10; ++k) { g0[k] = 0.f; g1[k] = 0.f; }

#pragma unroll 2
  for (int i = 0; i < 8; ++i) {
    int tile = tile0 + i;
    const int* fp = fidxP + ((size_t)tile * 16 + col) * 12 + odd * 6;
    int4 T = *(const int4_u*)fp;                // 4 taps of my parity
    int  T4 = fp[4];                            // 5th tap
    f32x4 acc0 = {0.f, 0.f, 0.f, 0.f};
    f32x4 acc1 = {0.f, 0.f, 0.f, 0.f};
    bf16x8 A;
    A = *(const bf16x8*)(hb + T.x);
    acc0 = __builtin_amdgcn_mfma_f32_16x16x32_bf16(A, Bf[0], acc0, 0, 0, 0);
    acc1 = __builtin_amdgcn_mfma_f32_16x16x32_bf16(A, Bf[1], acc1, 0, 0, 0);
    A = *(const bf16x8*)(hb + T.y);
    acc0 = __builtin_amdgcn_mfma_f32_16x16x32_bf16(A, Bf[2], acc0, 0, 0, 0);
    acc1 = __builtin_amdgcn_mfma_f32_16x16x32_bf16(A, Bf[3], acc1, 0, 0, 0);
    A = *(const bf16x8*)(hb + T.z);
    acc0 = __builtin_amdgcn_mfma_f32_16x16x32_bf16(A, Bf[4], acc0, 0, 0, 0);
    acc1 = __builtin_amdgcn_mfma_f32_16x16x32_bf16(A, Bf[5], acc1, 0, 0, 0);
    A = *(const bf16x8*)(hb + T.w);
    acc0 = __builtin_amdgcn_mfma_f32_16x16x32_bf16(A, Bf[6], acc0, 0, 0, 0);
    acc1 = __builtin_amdgcn_mfma_f32_16x16x32_bf16(A, Bf[7], acc1, 0, 0, 0);
    A = *(const bf16x8*)(hb + T4);
    acc0 = __builtin_amdgcn_mfma_f32_16x16x32_bf16(A, Bf[8], acc0, 0, 0, 0);
    acc1 = __builtin_amdgcn_mfma_f32_16x16x32_bf16(A, Bf[9], acc1, 0, 0, 0);
    float m0 = fmaxf(fmaxf(acc0[0], acc0[1]), fmaxf(acc0[2], acc0[3])) + bias0;
    float m1 = fmaxf(fmaxf(acc1[0], acc1[1]), fmaxf(acc1[2], acc1[3])) + bias1;
    int j = tile * 4 + (lane >> 4);
    // A-row broadcast across the 16 lanes of this hi-group (same j)
    const float* ar = A12 + (size_t)j * 12;
    float4 a0 = *(const float4*)ar;
    float4 a1 = *(const float4*)(ar + 4);
    float2 a2 = *(const float2*)(ar + 8);
    float av[10] = {a0.x, a0.y, a0.z, a0.w, a1.x, a1.y, a1.z, a1.w, a2.x, a2.y};
#pragma unroll
    for (int k = 0; k < 10; ++k) {
      g0[k] = fmaf(m0, av[k], g0[k]);
      g1[k] = fmaf(m1, av[k], g1[k]);
    }
  }
  // reduce the 4 hi-groups (same col -> same c) within the wave
#pragma unroll
  for (int k = 0; k < 10; ++k) {
    g0[k] += __shfl_xor(g0[k], 16); g0[k] += __shfl_xor(g0[k], 32);
    g1[k] += __shfl_xor(g1[k], 16); g1[k] += __shfl_xor(g1[k], 32);
  }
  if (lane < 16) {
#pragma unroll
    for (int k = 0; k < 10; ++k) {
      atomicAdd(&GL[col * 10 + k], g0[k]);
      atomicAdd(&GL[(col + 16) * 10 + k], g1[k]);
    }
  }
  __syncthreads();
  for (int i = threadIdx.x; i < 320; i += 256)
    atomicAdd(&G[b * 320 + i], GL[i]);
}

// ---- out[b][o] += (1/N2) * sum_{c,k} w3t[k][c][o] * G[b][c][k] ----
__global__ __launch_bounds__(256) void k3c(
    const float* __restrict__ G, const float* __restrict__ w3t,
    float* __restrict__ out) {
  int t = blockIdx.x * 256 + threadIdx.x;       // 2560 threads
  int pair = t >> 5, c = t & 31;
  int b = pair / 10, o = pair % 10;
  float s = 0.f;
#pragma unroll
  for (int k = 0; k < KC; ++k)
    s += G[b * 320 + c * 10 + k] * w3t[k * 320 + c * 10 + o];
#pragma unroll
  for (int off = 1; off < 32; off <<= 1) s += __shfl_xor(s, off);
  if ((threadIdx.x & 31) == 0) atomicAdd(&out[pair], s * (1.0f / N2));
}

extern "C" void kernel_launch(void* const* d_in, const int* in_sizes, int n_in,
                              void* d_out, int out_size, void* d_ws, size_t ws_size,
                              hipStream_t stream) {
  const float* x       = (const float*)d_in[0];
  const int*   conv_t0 = (const int*)d_in[1];
  const int*   conv_t1 = (const int*)d_in[2];
  const int*   conv_t2 = (const int*)d_in[3];
  const int*   adj0    = (const int*)d_in[4];
  const int*   adj1    = (const int*)d_in[5];
  const int*   pool0   = (const int*)d_in[6];
  const int*   pool1   = (const int*)d_in[7];
  const float* w1      = (const float*)d_in[8];
  const float* b1      = (const float*)d_in[9];
  const float* w2      = (const float*)d_in[10];
  const float* b2      = (const float*)d_in[11];
  const float* w3      = (const float*)d_in[12];
  const float* b3      = (const float*)d_in[13];
  float* out  = (float*)d_out;
  float* wsf  = (float*)d_ws;

  // words: xT64 [N0][16w] 5,242,880 | h2 5,242,880 | fidxM 3,932,160 |
  // fidxP 983,040 | A12 245,760 | G 2,560 | wB1 512 | wB 2,560 | w3t 3,200
  // (h3 eliminated by the k2/k3b fusion)
  uint4* xT64  = (uint4*)wsf;                   // dead after k1
  unsigned short* h2b = (unsigned short*)(wsf + 5242880);
  int* fidxM   = (int*)(wsf + 2 * 5242880);
  int* fidxP   = fidxM + (size_t)N1 * 4 * 12;
  float* A12   = (float*)(fidxP + (size_t)N2 * 4 * 12);
  float* G     = A12 + (size_t)N2 * 12;
  unsigned short* wB1 = (unsigned short*)(G + 2560);
  unsigned short* wB  = wB1 + 1024;
  float* w3t   = (float*)(wB + 5120);

  hipMemsetAsync(A12, 0, (size_t)(N2 * 12 + 2560) * 4, stream);  // A12 + G
  kpre<<<3380, 256, 0, stream>>>(x, xT64, conv_t0, conv_t1, conv_t2,
                                 adj0, adj1, pool0, pool1,
                                 fidxM, fidxP, A12,
                                 w1, w2, w3, b3, wB1, wB, w3t, out);
  k1<<<5120, 256, 0, stream>>>((const char*)xT64, fidxM, (const bf16x8*)wB1, b1, h2b);
  k2<<<1280, 256, 0, stream>>>((const char*)h2b, fidxP, A12, (const bf16x8*)wB, b2, G);
  k3c<<<10, 256, 0, stream>>>(G, w3t, out);
}